// Round 2
// baseline (304.482 us; speedup 1.0000x reference)
//
#include <hip/hip_runtime.h>

#define KN 1000000
#define NCOLS 70400
#define NPAIRS (KN / 32)          // 2 tiles (32 elems) per wave-iteration
#define NBLK 1536
#define NTHR 256

typedef _Float16 f16x8 __attribute__((ext_vector_type(8)));
typedef float    f32x4 __attribute__((ext_vector_type(4)));

__device__ __forceinline__ unsigned encodeF(float f) {
    unsigned b = __float_as_uint(f);
    return (b & 0x80000000u) ? ~b : (b | 0x80000000u);
}
__device__ __forceinline__ float decodeF(unsigned e) {
    unsigned b = (e & 0x80000000u) ? (e & 0x7fffffffu) : ~e;
    return __uint_as_float(b);
}
#define ENC_SENT 0x34E76980u   // encodeF(-9999999.0f)

#define MFMA16(a, b, c) __builtin_amdgcn_mfma_f32_16x16x32_f16((a), (b), (c), 0, 0, 0)

// LDS layout of raw fp32 weights (staged coalesced once per block):
#define OW1 0
#define OB1 72
#define OW2 90
#define OB2 738
#define OW3 774
#define OB3 2070
#define OW4 2106
#define OB4 2142
#define NWTS 2143

// MFMA 16x16x32 f16 layouts (gfx950): A[m][k]: m=lane&15, k=(lane>>4)*8+j;
// D[m][n]: n=lane&15, m=(lane>>4)*4+reg.  D(elem x out) = A(elem x in) * B(W^T).
// R11: counters showed dur=56us with WRITE_SIZE=43.5MB for a 281KB table
// (~44B HBM write per atomic) and all pipes <30% busy -> atomic-contention
// bound (~14 same-address dependent RMWs per output column serialize at the
// memory side). Fix: prefetch outU[col] one iter ahead (monotone table ->
// stale reads are safe) and skip atomics that cannot win; expected successful
// updates per column ~H(14)=3.3 -> ~3x fewer atomics and ~3x shorter
// same-address chains. Also 1024->1536 blocks (6 blocks/CU, 162.8KB/160KiB
// LDS fit, 24 waves/CU) for latency hiding.

__global__ __launch_bounds__(NTHR)
__attribute__((amdgpu_waves_per_eu(6, 6)))
void mlp_scatter_mfma(const float* __restrict__ x, const int* __restrict__ tidx,
                      const float* __restrict__ W1, const float* __restrict__ b1,
                      const float* __restrict__ W2, const float* __restrict__ b2,
                      const float* __restrict__ W3, const float* __restrict__ b3,
                      const float* __restrict__ W4, const float* __restrict__ b4,
                      unsigned* __restrict__ outU)
{
    __shared__ float    sw[NWTS];           // raw fp32 weights, block-shared
    __shared__ _Float16 smem[4][2][1152];   // 4 waves x 2 tiles x (16*72) halfs

    const int t    = threadIdx.x;
    const int lane = t & 63;
    const int wv   = t >> 6;
    const int quad = lane >> 4;
    const int n    = lane & 15;

    // ---- coalesced one-time stage of all weights into LDS ----
    for (int i = t; i < 72;   i += NTHR) sw[OW1 + i] = W1[i];
    for (int i = t; i < 18;   i += NTHR) sw[OB1 + i] = b1[i];
    for (int i = t; i < 648;  i += NTHR) sw[OW2 + i] = W2[i];
    for (int i = t; i < 36;   i += NTHR) sw[OB2 + i] = b2[i];
    for (int i = t; i < 1296; i += NTHR) sw[OW3 + i] = W3[i];
    for (int i = t; i < 36;   i += NTHR) sw[OB3 + i] = b3[i];
    for (int i = t; i < 36;   i += NTHR) sw[OW4 + i] = W4[i];
    if (t == 0) sw[OB4] = b4[0];

    _Float16* Ha = &smem[wv][0][0];
    _Float16* Hb = &smem[wv][1][0];

    // one-time zero of cols 48..63 (all 16 rows) in both tile buffers
    for (int i = lane; i < 128; i += 64) {
        const int row = i >> 3, dc = i & 7;
        ((unsigned*)(Ha + row * 72 + 48))[dc] = 0u;
        ((unsigned*)(Hb + row * 72 + 48))[dc] = 0u;
    }
    __syncthreads();

    // ---- weight B-fragments, built once per wave from LDS (no TA cost) ----
    auto bf = [&](int off, int OUT, int IN, int tt, int ks) {
        f16x8 r;
#pragma unroll
        for (int j = 0; j < 8; ++j) {
            int k  = ks * 32 + quad * 8 + j;
            int ng = tt * 16 + n;
            float w = (ng < OUT && k < IN) ? sw[off + ng * IN + k] : 0.0f;
            r[j] = (_Float16)w;
        }
        return r;
    };
    const f16x8 B1_0 = bf(OW1, 18,  4, 0, 0), B1_1 = bf(OW1, 18,  4, 1, 0);
    const f16x8 B2_0 = bf(OW2, 36, 18, 0, 0), B2_1 = bf(OW2, 36, 18, 1, 0), B2_2 = bf(OW2, 36, 18, 2, 0);
    const f16x8 B3_00 = bf(OW3, 36, 36, 0, 0), B3_01 = bf(OW3, 36, 36, 0, 1);
    const f16x8 B3_10 = bf(OW3, 36, 36, 1, 0), B3_11 = bf(OW3, 36, 36, 1, 1);
    const f16x8 B3_20 = bf(OW3, 36, 36, 2, 0), B3_21 = bf(OW3, 36, 36, 2, 1);

    const float bias1_0 = sw[OB1 + n];
    const float bias1_1 = (n < 2) ? sw[OB1 + 16 + n] : 0.0f;
    const float bias2_0 = sw[OB2 + n], bias2_1 = sw[OB2 + 16 + n];
    const float bias2_2 = (n < 4) ? sw[OB2 + 32 + n] : 0.0f;
    const float bias3_0 = sw[OB3 + n], bias3_1 = sw[OB3 + 16 + n];
    const float bias3_2 = (n < 4) ? sw[OB3 + 32 + n] : 0.0f;
    const float b4s = sw[OB4];
    const float w4_0 = sw[OW4 + n], w4_1 = sw[OW4 + 16 + n];
    const float w4_2 = (n < 4) ? sw[OW4 + 32 + n] : 0.0f;

    const int gw = (blockIdx.x * blockDim.x + t) >> 6;
    const int nw = (gridDim.x * blockDim.x) >> 6;

    // ---- prefetch-rotate state for pair p ----
    float cxa0, cxa1, cxa2, cxa3, cxb0, cxb1, cxb2, cxb3;
    int cca = 0, ccb = 0;
    unsigned csa = 0u, csb = 0u;
    if (gw < NPAIRS) {
        const int kb = gw * 32;
        cxa0 = x[0 * KN + kb + n];      cxb0 = x[0 * KN + kb + 16 + n];
        cxa1 = x[1 * KN + kb + n];      cxb1 = x[1 * KN + kb + 16 + n];
        cxa2 = x[2 * KN + kb + n];      cxb2 = x[2 * KN + kb + 16 + n];
        cxa3 = x[3 * KN + kb + n];      cxb3 = x[3 * KN + kb + 16 + n];
        cca  = tidx[2 * (kb + n) + 1];  ccb  = tidx[2 * (kb + 16 + n) + 1];
        csa  = outU[cca];               csb  = outU[ccb];   // stale-safe (monotone)
    }

    for (int p = gw; p < NPAIRS; ) {
        const int pn = p + nw;
        const float xa0 = cxa0, xa1 = cxa1, xa2 = cxa2, xa3 = cxa3;
        const float xb0 = cxb0, xb1 = cxb1, xb2 = cxb2, xb3 = cxb3;
        const int cola = cca, colb = ccb;
        const unsigned seenA = csa, seenB = csb;
        if (pn < NPAIRS) {
            const int kb = pn * 32;
            cxa0 = x[0 * KN + kb + n];      cxb0 = x[0 * KN + kb + 16 + n];
            cxa1 = x[1 * KN + kb + n];      cxb1 = x[1 * KN + kb + 16 + n];
            cxa2 = x[2 * KN + kb + n];      cxb2 = x[2 * KN + kb + 16 + n];
            cxa3 = x[3 * KN + kb + n];      cxb3 = x[3 * KN + kb + 16 + n];
            cca  = tidx[2 * (kb + n) + 1];  ccb  = tidx[2 * (kb + 16 + n) + 1];
            csa  = outU[cca];               csb  = outU[ccb];
        }

        // ---- L1: A-frags direct from x (real k<4, quad 0 only) ----
        f16x8 a1a = {}, a1b = {};
        if (quad == 0) {
            a1a[0] = (_Float16)xa0; a1a[1] = (_Float16)xa1;
            a1a[2] = (_Float16)xa2; a1a[3] = (_Float16)xa3;
            a1b[0] = (_Float16)xb0; a1b[1] = (_Float16)xb1;
            a1b[2] = (_Float16)xb2; a1b[3] = (_Float16)xb3;
        }
        f32x4 c0a = {bias1_0, bias1_0, bias1_0, bias1_0};
        f32x4 c1a = {bias1_1, bias1_1, bias1_1, bias1_1};
        f32x4 c0b = c0a, c1b = c1a;
        c0a = MFMA16(a1a, B1_0, c0a);  c0b = MFMA16(a1b, B1_0, c0b);
        c1a = MFMA16(a1a, B1_1, c1a);  c1b = MFMA16(a1b, B1_1, c1b);
#pragma unroll
        for (int r = 0; r < 4; ++r) {
            const int row = (quad * 4 + r) * 72;
            Ha[row + n]      = (_Float16)fmaxf(c0a[r], 0.0f);
            Ha[row + 16 + n] = (_Float16)fmaxf(c1a[r], 0.0f);
            Hb[row + n]      = (_Float16)fmaxf(c0b[r], 0.0f);
            Hb[row + 16 + n] = (_Float16)fmaxf(c1b[r], 0.0f);
        }

        // ---- L2: read A (k 0..31), 3 MFMA per tile, overwrite cols 0..47 ----
        const f16x8 a2a = *(const f16x8*)&Ha[n * 72 + quad * 8];
        const f16x8 a2b = *(const f16x8*)&Hb[n * 72 + quad * 8];
        f32x4 d0a = {bias2_0, bias2_0, bias2_0, bias2_0};
        f32x4 d1a = {bias2_1, bias2_1, bias2_1, bias2_1};
        f32x4 d2a = {bias2_2, bias2_2, bias2_2, bias2_2};
        f32x4 d0b = d0a, d1b = d1a, d2b = d2a;
        d0a = MFMA16(a2a, B2_0, d0a);  d0b = MFMA16(a2b, B2_0, d0b);
        d1a = MFMA16(a2a, B2_1, d1a);  d1b = MFMA16(a2b, B2_1, d1b);
        d2a = MFMA16(a2a, B2_2, d2a);  d2b = MFMA16(a2b, B2_2, d2b);
#pragma unroll
        for (int r = 0; r < 4; ++r) {
            const int row = (quad * 4 + r) * 72;
            Ha[row + n]      = (_Float16)fmaxf(d0a[r], 0.0f);
            Ha[row + 16 + n] = (_Float16)fmaxf(d1a[r], 0.0f);
            Ha[row + 32 + n] = (_Float16)fmaxf(d2a[r], 0.0f);
            Hb[row + n]      = (_Float16)fmaxf(d0b[r], 0.0f);
            Hb[row + 16 + n] = (_Float16)fmaxf(d1b[r], 0.0f);
            Hb[row + 32 + n] = (_Float16)fmaxf(d2b[r], 0.0f);
        }

        // ---- L3: 6 MFMA per tile (k real 36; k>=36 B-weights are zero) ----
        const f16x8 a30a = *(const f16x8*)&Ha[n * 72 + quad * 8];
        const f16x8 a31a = *(const f16x8*)&Ha[n * 72 + 32 + quad * 8];
        const f16x8 a30b = *(const f16x8*)&Hb[n * 72 + quad * 8];
        const f16x8 a31b = *(const f16x8*)&Hb[n * 72 + 32 + quad * 8];
        f32x4 e0a = {bias3_0, bias3_0, bias3_0, bias3_0};
        f32x4 e1a = {bias3_1, bias3_1, bias3_1, bias3_1};
        f32x4 e2a = {bias3_2, bias3_2, bias3_2, bias3_2};
        f32x4 e0b = e0a, e1b = e1a, e2b = e2a;
        e0a = MFMA16(a30a, B3_00, e0a);  e0a = MFMA16(a31a, B3_01, e0a);
        e1a = MFMA16(a30a, B3_10, e1a);  e1a = MFMA16(a31a, B3_11, e1a);
        e2a = MFMA16(a30a, B3_20, e2a);  e2a = MFMA16(a31a, B3_21, e2a);
        e0b = MFMA16(a30b, B3_00, e0b);  e0b = MFMA16(a31b, B3_01, e0b);
        e1b = MFMA16(a30b, B3_10, e1b);  e1b = MFMA16(a31b, B3_11, e1b);
        e2b = MFMA16(a30b, B3_20, e2b);  e2b = MFMA16(a31b, B3_21, e2b);

        // ---- L4 in VALU: v[elem] = sum_out W4[out]*relu(h3[elem][out]) ----
        float pa[4], pb[4];
#pragma unroll
        for (int r = 0; r < 4; ++r) {
            pa[r] = fmaf(w4_0, fmaxf(e0a[r], 0.0f),
                    fmaf(w4_1, fmaxf(e1a[r], 0.0f),
                         w4_2 * fmaxf(e2a[r], 0.0f)));
            pb[r] = fmaf(w4_0, fmaxf(e0b[r], 0.0f),
                    fmaf(w4_1, fmaxf(e1b[r], 0.0f),
                         w4_2 * fmaxf(e2b[r], 0.0f)));
        }
#pragma unroll
        for (int m = 8; m >= 1; m >>= 1) {
#pragma unroll
            for (int r = 0; r < 4; ++r) {
                pa[r] += __shfl_xor(pa[r], m, 16);
                pb[r] += __shfl_xor(pb[r], m, 16);
            }
        }
        if ((n >> 2) == quad) {
            const int r = n & 3;
            const unsigned ea = encodeF(pa[r] + b4s) - ENC_SENT;
            const unsigned eb = encodeF(pb[r] + b4s) - ENC_SENT;
            // monotone table: stale 'seen' can only cause a redundant atomic,
            // never a wrong skip
            if (ea > seenA) atomicMax(&outU[cola], ea);
            if (eb > seenB) atomicMax(&outU[colb], eb);
        }

        p = pn;
    }
}

__global__ __launch_bounds__(256) void init_kernel(unsigned* __restrict__ outU) {
    int gid = blockIdx.x * blockDim.x + threadIdx.x;
    if (gid < NCOLS) outU[gid] = 0u;   // == encode(SENTINEL) - bias
}

__global__ __launch_bounds__(256) void decode_kernel(unsigned* __restrict__ outU,
                                                     int out_size) {
    int gid = blockIdx.x * blockDim.x + threadIdx.x;
    if (gid < out_size) {
        float r = (gid < NCOLS) ? decodeF(outU[gid] + ENC_SENT) : 1.0f;
        ((float*)outU)[gid] = r;
    }
}

extern "C" void kernel_launch(void* const* d_in, const int* in_sizes, int n_in,
                              void* d_out, int out_size, void* d_ws, size_t ws_size,
                              hipStream_t stream) {
    const float* x    = (const float*)d_in[0];   // (1,4,1,K)
    const int*   tidx = (const int*)d_in[1];     // (K,2)
    const float* W1 = (const float*)d_in[2];
    const float* b1 = (const float*)d_in[3];
    const float* W2 = (const float*)d_in[4];
    const float* b2 = (const float*)d_in[5];
    const float* W3 = (const float*)d_in[6];
    const float* b3 = (const float*)d_in[7];
    const float* W4 = (const float*)d_in[8];
    const float* b4 = (const float*)d_in[9];
    unsigned* outU = (unsigned*)d_out;

    init_kernel<<<(NCOLS + 255) / 256, 256, 0, stream>>>(outU);

    mlp_scatter_mfma<<<NBLK, NTHR, 0, stream>>>(
        x, tidx, W1, b1, W2, b2, W3, b3, W4, b4, outU);

    decode_kernel<<<(out_size + 255) / 256, 256, 0, stream>>>(outU, out_size);
}

// Round 3
// 136.586 us; speedup vs baseline: 2.2292x; 2.2292x over previous
//
#include <hip/hip_runtime.h>

#define KN 1000000
#define NCOLS 70400
#define NPAIRS (KN / 32)          // 2 tiles (32 elems) per wave-iteration
#define NBLK 1024
#define NTHR 256
#define NREP_MAX 8

typedef _Float16 f16x8 __attribute__((ext_vector_type(8)));
typedef float    f32x4 __attribute__((ext_vector_type(4)));

__device__ __forceinline__ unsigned encodeF(float f) {
    unsigned b = __float_as_uint(f);
    return (b & 0x80000000u) ? ~b : (b | 0x80000000u);
}
__device__ __forceinline__ float decodeF(unsigned e) {
    unsigned b = (e & 0x80000000u) ? (e & 0x7fffffffu) : ~e;
    return __uint_as_float(b);
}
#define ENC_SENT 0x34E76980u   // encodeF(-9999999.0f)

#define MFMA16(a, b, c) __builtin_amdgcn_mfma_f32_16x16x32_f16((a), (b), (c), 0, 0, 0)

// LDS layout of raw fp32 weights (staged coalesced once per block):
#define OW1 0
#define OB1 72
#define OW2 90
#define OB2 738
#define OW3 774
#define OB3 2070
#define OW4 2106
#define OB4 2142
#define NWTS 2143

// R11 history: R1 = 56us main kernel, MfmaUtil 7%, VALUBusy 28%, WRITE=43.5MB
// for a 281KB table (~44B HBM write per atomic) -> atomic-bound.
// R2 (read-before-atomic filter) FAILED: FETCH 18->380MB, dur->230us. Plain
// cached reads of lines under concurrent device-scope atomics ping-pong at the
// coherence point (atomics invalidate per-XCD L2 copies -> every read misses).
// NEVER mix cached reads with hot device-scope atomics on the same lines.
// R3: attack the same-line dependent RMW chain instead, with ZERO reads:
// replicate the accumulator table 8x in d_ws (8 x 281KB), wave gw atomics into
// replica (gw & 7); decode kernel merges the replicas. Max same-line chain
// 227 -> ~28. Everything else identical to R1 (NBLK=1024, waves_per_eu 4).

__global__ __launch_bounds__(NTHR)
__attribute__((amdgpu_waves_per_eu(4, 4)))
void mlp_scatter_mfma(const float* __restrict__ x, const int* __restrict__ tidx,
                      const float* __restrict__ W1, const float* __restrict__ b1,
                      const float* __restrict__ W2, const float* __restrict__ b2,
                      const float* __restrict__ W3, const float* __restrict__ b3,
                      const float* __restrict__ W4, const float* __restrict__ b4,
                      unsigned* __restrict__ rep, int rmask)
{
    __shared__ float    sw[NWTS];           // raw fp32 weights, block-shared
    __shared__ _Float16 smem[4][2][1152];   // 4 waves x 2 tiles x (16*72) halfs

    const int t    = threadIdx.x;
    const int lane = t & 63;
    const int wv   = t >> 6;
    const int quad = lane >> 4;
    const int n    = lane & 15;

    // ---- coalesced one-time stage of all weights into LDS ----
    for (int i = t; i < 72;   i += NTHR) sw[OW1 + i] = W1[i];
    for (int i = t; i < 18;   i += NTHR) sw[OB1 + i] = b1[i];
    for (int i = t; i < 648;  i += NTHR) sw[OW2 + i] = W2[i];
    for (int i = t; i < 36;   i += NTHR) sw[OB2 + i] = b2[i];
    for (int i = t; i < 1296; i += NTHR) sw[OW3 + i] = W3[i];
    for (int i = t; i < 36;   i += NTHR) sw[OB3 + i] = b3[i];
    for (int i = t; i < 36;   i += NTHR) sw[OW4 + i] = W4[i];
    if (t == 0) sw[OB4] = b4[0];

    _Float16* Ha = &smem[wv][0][0];
    _Float16* Hb = &smem[wv][1][0];

    // one-time zero of cols 48..63 (all 16 rows) in both tile buffers
    for (int i = lane; i < 128; i += 64) {
        const int row = i >> 3, dc = i & 7;
        ((unsigned*)(Ha + row * 72 + 48))[dc] = 0u;
        ((unsigned*)(Hb + row * 72 + 48))[dc] = 0u;
    }
    __syncthreads();

    // ---- weight B-fragments, built once per wave from LDS (no TA cost) ----
    auto bf = [&](int off, int OUT, int IN, int tt, int ks) {
        f16x8 r;
#pragma unroll
        for (int j = 0; j < 8; ++j) {
            int k  = ks * 32 + quad * 8 + j;
            int ng = tt * 16 + n;
            float w = (ng < OUT && k < IN) ? sw[off + ng * IN + k] : 0.0f;
            r[j] = (_Float16)w;
        }
        return r;
    };
    const f16x8 B1_0 = bf(OW1, 18,  4, 0, 0), B1_1 = bf(OW1, 18,  4, 1, 0);
    const f16x8 B2_0 = bf(OW2, 36, 18, 0, 0), B2_1 = bf(OW2, 36, 18, 1, 0), B2_2 = bf(OW2, 36, 18, 2, 0);
    const f16x8 B3_00 = bf(OW3, 36, 36, 0, 0), B3_01 = bf(OW3, 36, 36, 0, 1);
    const f16x8 B3_10 = bf(OW3, 36, 36, 1, 0), B3_11 = bf(OW3, 36, 36, 1, 1);
    const f16x8 B3_20 = bf(OW3, 36, 36, 2, 0), B3_21 = bf(OW3, 36, 36, 2, 1);

    const float bias1_0 = sw[OB1 + n];
    const float bias1_1 = (n < 2) ? sw[OB1 + 16 + n] : 0.0f;
    const float bias2_0 = sw[OB2 + n], bias2_1 = sw[OB2 + 16 + n];
    const float bias2_2 = (n < 4) ? sw[OB2 + 32 + n] : 0.0f;
    const float bias3_0 = sw[OB3 + n], bias3_1 = sw[OB3 + 16 + n];
    const float bias3_2 = (n < 4) ? sw[OB3 + 32 + n] : 0.0f;
    const float b4s = sw[OB4];
    const float w4_0 = sw[OW4 + n], w4_1 = sw[OW4 + 16 + n];
    const float w4_2 = (n < 4) ? sw[OW4 + 32 + n] : 0.0f;

    const int gw = (blockIdx.x * blockDim.x + t) >> 6;
    const int nw = (gridDim.x * blockDim.x) >> 6;

    // replica base for this wave's atomics (spreads same-line chains)
    unsigned* __restrict__ dst = rep + (size_t)(gw & rmask) * NCOLS;

    // ---- prefetch-rotate state for pair p ----
    float cxa0, cxa1, cxa2, cxa3, cxb0, cxb1, cxb2, cxb3;
    int cca = 0, ccb = 0;
    if (gw < NPAIRS) {
        const int kb = gw * 32;
        cxa0 = x[0 * KN + kb + n];      cxb0 = x[0 * KN + kb + 16 + n];
        cxa1 = x[1 * KN + kb + n];      cxb1 = x[1 * KN + kb + 16 + n];
        cxa2 = x[2 * KN + kb + n];      cxb2 = x[2 * KN + kb + 16 + n];
        cxa3 = x[3 * KN + kb + n];      cxb3 = x[3 * KN + kb + 16 + n];
        cca  = tidx[2 * (kb + n) + 1];  ccb  = tidx[2 * (kb + 16 + n) + 1];
    }

    for (int p = gw; p < NPAIRS; ) {
        const int pn = p + nw;
        const float xa0 = cxa0, xa1 = cxa1, xa2 = cxa2, xa3 = cxa3;
        const float xb0 = cxb0, xb1 = cxb1, xb2 = cxb2, xb3 = cxb3;
        const int cola = cca, colb = ccb;
        if (pn < NPAIRS) {
            const int kb = pn * 32;
            cxa0 = x[0 * KN + kb + n];      cxb0 = x[0 * KN + kb + 16 + n];
            cxa1 = x[1 * KN + kb + n];      cxb1 = x[1 * KN + kb + 16 + n];
            cxa2 = x[2 * KN + kb + n];      cxb2 = x[2 * KN + kb + 16 + n];
            cxa3 = x[3 * KN + kb + n];      cxb3 = x[3 * KN + kb + 16 + n];
            cca  = tidx[2 * (kb + n) + 1];  ccb  = tidx[2 * (kb + 16 + n) + 1];
        }

        // ---- L1: A-frags direct from x (real k<4, quad 0 only) ----
        f16x8 a1a = {}, a1b = {};
        if (quad == 0) {
            a1a[0] = (_Float16)xa0; a1a[1] = (_Float16)xa1;
            a1a[2] = (_Float16)xa2; a1a[3] = (_Float16)xa3;
            a1b[0] = (_Float16)xb0; a1b[1] = (_Float16)xb1;
            a1b[2] = (_Float16)xb2; a1b[3] = (_Float16)xb3;
        }
        f32x4 c0a = {bias1_0, bias1_0, bias1_0, bias1_0};
        f32x4 c1a = {bias1_1, bias1_1, bias1_1, bias1_1};
        f32x4 c0b = c0a, c1b = c1a;
        c0a = MFMA16(a1a, B1_0, c0a);  c0b = MFMA16(a1b, B1_0, c0b);
        c1a = MFMA16(a1a, B1_1, c1a);  c1b = MFMA16(a1b, B1_1, c1b);
#pragma unroll
        for (int r = 0; r < 4; ++r) {
            const int row = (quad * 4 + r) * 72;
            Ha[row + n]      = (_Float16)fmaxf(c0a[r], 0.0f);
            Ha[row + 16 + n] = (_Float16)fmaxf(c1a[r], 0.0f);
            Hb[row + n]      = (_Float16)fmaxf(c0b[r], 0.0f);
            Hb[row + 16 + n] = (_Float16)fmaxf(c1b[r], 0.0f);
        }

        // ---- L2: read A (k 0..31), 3 MFMA per tile, overwrite cols 0..47 ----
        const f16x8 a2a = *(const f16x8*)&Ha[n * 72 + quad * 8];
        const f16x8 a2b = *(const f16x8*)&Hb[n * 72 + quad * 8];
        f32x4 d0a = {bias2_0, bias2_0, bias2_0, bias2_0};
        f32x4 d1a = {bias2_1, bias2_1, bias2_1, bias2_1};
        f32x4 d2a = {bias2_2, bias2_2, bias2_2, bias2_2};
        f32x4 d0b = d0a, d1b = d1a, d2b = d2a;
        d0a = MFMA16(a2a, B2_0, d0a);  d0b = MFMA16(a2b, B2_0, d0b);
        d1a = MFMA16(a2a, B2_1, d1a);  d1b = MFMA16(a2b, B2_1, d1b);
        d2a = MFMA16(a2a, B2_2, d2a);  d2b = MFMA16(a2b, B2_2, d2b);
#pragma unroll
        for (int r = 0; r < 4; ++r) {
            const int row = (quad * 4 + r) * 72;
            Ha[row + n]      = (_Float16)fmaxf(d0a[r], 0.0f);
            Ha[row + 16 + n] = (_Float16)fmaxf(d1a[r], 0.0f);
            Ha[row + 32 + n] = (_Float16)fmaxf(d2a[r], 0.0f);
            Hb[row + n]      = (_Float16)fmaxf(d0b[r], 0.0f);
            Hb[row + 16 + n] = (_Float16)fmaxf(d1b[r], 0.0f);
            Hb[row + 32 + n] = (_Float16)fmaxf(d2b[r], 0.0f);
        }

        // ---- L3: 6 MFMA per tile (k real 36; k>=36 B-weights are zero) ----
        const f16x8 a30a = *(const f16x8*)&Ha[n * 72 + quad * 8];
        const f16x8 a31a = *(const f16x8*)&Ha[n * 72 + 32 + quad * 8];
        const f16x8 a30b = *(const f16x8*)&Hb[n * 72 + quad * 8];
        const f16x8 a31b = *(const f16x8*)&Hb[n * 72 + 32 + quad * 8];
        f32x4 e0a = {bias3_0, bias3_0, bias3_0, bias3_0};
        f32x4 e1a = {bias3_1, bias3_1, bias3_1, bias3_1};
        f32x4 e2a = {bias3_2, bias3_2, bias3_2, bias3_2};
        f32x4 e0b = e0a, e1b = e1a, e2b = e2a;
        e0a = MFMA16(a30a, B3_00, e0a);  e0a = MFMA16(a31a, B3_01, e0a);
        e1a = MFMA16(a30a, B3_10, e1a);  e1a = MFMA16(a31a, B3_11, e1a);
        e2a = MFMA16(a30a, B3_20, e2a);  e2a = MFMA16(a31a, B3_21, e2a);
        e0b = MFMA16(a30b, B3_00, e0b);  e0b = MFMA16(a31b, B3_01, e0b);
        e1b = MFMA16(a30b, B3_10, e1b);  e1b = MFMA16(a31b, B3_11, e1b);
        e2b = MFMA16(a30b, B3_20, e2b);  e2b = MFMA16(a31b, B3_21, e2b);

        // ---- L4 in VALU: v[elem] = sum_out W4[out]*relu(h3[elem][out]) ----
        float pa[4], pb[4];
#pragma unroll
        for (int r = 0; r < 4; ++r) {
            pa[r] = fmaf(w4_0, fmaxf(e0a[r], 0.0f),
                    fmaf(w4_1, fmaxf(e1a[r], 0.0f),
                         w4_2 * fmaxf(e2a[r], 0.0f)));
            pb[r] = fmaf(w4_0, fmaxf(e0b[r], 0.0f),
                    fmaf(w4_1, fmaxf(e1b[r], 0.0f),
                         w4_2 * fmaxf(e2b[r], 0.0f)));
        }
#pragma unroll
        for (int m = 8; m >= 1; m >>= 1) {
#pragma unroll
            for (int r = 0; r < 4; ++r) {
                pa[r] += __shfl_xor(pa[r], m, 16);
                pb[r] += __shfl_xor(pb[r], m, 16);
            }
        }
        if ((n >> 2) == quad) {
            const int r = n & 3;
            atomicMax(&dst[cola], encodeF(pa[r] + b4s) - ENC_SENT);
            atomicMax(&dst[colb], encodeF(pb[r] + b4s) - ENC_SENT);
        }

        p = pn;
    }
}

__global__ __launch_bounds__(256) void init_kernel(unsigned* __restrict__ rep,
                                                   int total) {
    int gid = blockIdx.x * blockDim.x + threadIdx.x;
    if (gid < total) rep[gid] = 0u;   // == encode(SENTINEL) - bias
}

__global__ __launch_bounds__(256) void decode_kernel(const unsigned* __restrict__ rep,
                                                     int nrep,
                                                     float* __restrict__ out,
                                                     int out_size) {
    int gid = blockIdx.x * blockDim.x + threadIdx.x;
    if (gid < out_size) {
        float r = 1.0f;
        if (gid < NCOLS) {
            unsigned m = rep[gid];
            for (int i = 1; i < nrep; ++i) {
                unsigned v = rep[(size_t)i * NCOLS + gid];
                m = (v > m) ? v : m;
            }
            r = decodeF(m + ENC_SENT);
        }
        out[gid] = r;
    }
}

extern "C" void kernel_launch(void* const* d_in, const int* in_sizes, int n_in,
                              void* d_out, int out_size, void* d_ws, size_t ws_size,
                              hipStream_t stream) {
    const float* x    = (const float*)d_in[0];   // (1,4,1,K)
    const int*   tidx = (const int*)d_in[1];     // (K,2)
    const float* W1 = (const float*)d_in[2];
    const float* b1 = (const float*)d_in[3];
    const float* W2 = (const float*)d_in[4];
    const float* b2 = (const float*)d_in[5];
    const float* W3 = (const float*)d_in[6];
    const float* b3 = (const float*)d_in[7];
    const float* W4 = (const float*)d_in[8];
    const float* b4 = (const float*)d_in[9];

    // replica table: NREP copies in workspace if it fits, else accumulate in d_out
    int nrep = 1;
    unsigned* rep = (unsigned*)d_out;
    if (d_ws && ws_size >= (size_t)NREP_MAX * NCOLS * sizeof(unsigned)) {
        nrep = NREP_MAX;
        rep  = (unsigned*)d_ws;
    } else if (d_ws && ws_size >= (size_t)NCOLS * sizeof(unsigned)) {
        nrep = 1;
        rep  = (unsigned*)d_ws;
    }
    const int total = nrep * NCOLS;

    init_kernel<<<(total + 255) / 256, 256, 0, stream>>>(rep, total);

    mlp_scatter_mfma<<<NBLK, NTHR, 0, stream>>>(
        x, tidx, W1, b1, W2, b2, W3, b3, W4, b4, rep, nrep - 1);

    decode_kernel<<<(out_size + 255) / 256, 256, 0, stream>>>(
        rep, nrep, (float*)d_out, out_size);
}